// Round 9
// baseline (398.452 us; speedup 1.0000x reference)
//
#include <hip/hip_runtime.h>
#include <math.h>

#define NQ        14
#define DIM       16384          // 2^14
#define NLAYERS   5
#define NTHREADS  1024           // 16 amps/thread, 16 waves/block, 4 waves/SIMD

typedef float vf2 __attribute__((ext_vector_type(2)));
struct c32 { float x, y; };

// GF(2)-LINEAR layout: L(i) = i ^ sigma(i), sigma image in bits 3:0.
// L(a^b)=L(a)^L(b) -> every pass address = thread_base ^ compile-time const.
// Conflict-free for A/B/C/D patterns (16 distinct bank-pairs per 16-lane group;
// re-verified for the 4-bit windows).
__host__ __device__ constexpr int lswz(int i) {
    return i ^ ((i >> 4) & 15) ^ ((i >> 8) & 15) ^ ((i >> 12) & 3);
}
// Adjacent-pair parity of 4-bit j.
__host__ __device__ constexpr unsigned pjc(int j) {
    return (((j >> 3) & (j >> 2)) ^ ((j >> 2) & (j >> 1)) ^ ((j >> 1) & j)) & 1u;
}

__device__ __forceinline__ c32 cmul(c32 a, c32 b) {
    return { a.x * b.x - a.y * b.y, a.x * b.y + a.y * b.x };
}
__device__ __forceinline__ vf2 sxor(vf2 v, unsigned m) {
    return vf2{ __uint_as_float(__float_as_uint(v.x) ^ m),
                __uint_as_float(__float_as_uint(v.y) ^ m) };
}

// Complex butterfly in 8 VOP3P instrs (r7, verified).
__device__ __forceinline__ void bf(vf2 g0, vf2 g1, vf2 g2, vf2 g3,
                                   vf2& A0, vf2& A1) {
    vf2 b0, b1;
    asm("v_pk_mul_f32 %0, %3, %7 op_sel:[1,1] op_sel_hi:[1,0] neg_lo:[0,1] neg_hi:[0,0]\n\t"
        "v_pk_mul_f32 %1, %5, %7 op_sel:[1,1] op_sel_hi:[1,0] neg_lo:[0,1] neg_hi:[0,0]\n\t"
        "v_pk_fma_f32 %0, %3, %7, %0 op_sel:[0,0,0] op_sel_hi:[0,1,1]\n\t"
        "v_pk_fma_f32 %1, %5, %7, %1 op_sel:[0,0,0] op_sel_hi:[0,1,1]\n\t"
        "v_pk_fma_f32 %0, %2, %6, %0 op_sel:[1,1,0] op_sel_hi:[1,0,1] neg_lo:[0,1,0] neg_hi:[0,0,0]\n\t"
        "v_pk_fma_f32 %1, %4, %6, %1 op_sel:[1,1,0] op_sel_hi:[1,0,1] neg_lo:[0,1,0] neg_hi:[0,0,0]\n\t"
        "v_pk_fma_f32 %0, %2, %6, %0 op_sel:[0,0,0] op_sel_hi:[0,1,1]\n\t"
        "v_pk_fma_f32 %1, %4, %6, %1 op_sel:[0,0,0] op_sel_hi:[0,1,1]"
        : "=&v"(b0), "=&v"(b1)
        : "v"(g0), "v"(g1), "v"(g2), "v"(g3), "v"(A0), "v"(A1));
    A0 = b0; A1 = b1;
}

#define APPLY16(K, GG) { _Pragma("unroll") \
    for (int mm = 0; mm < 8; ++mm) { \
        const int r0 = ((mm >> (K)) << ((K) + 1)) | (mm & ((1 << (K)) - 1)); \
        bf((GG)[0], (GG)[1], (GG)[2], (GG)[3], aa[r0], aa[r0 | (1 << (K))]); } }

#define GL(gg, Gl, q) { gg[0] = (Gl)[q][0]; gg[1] = (Gl)[q][1]; \
                        gg[2] = (Gl)[q][2]; gg[3] = (Gl)[q][3]; }

// Ring-sign mask: identical structure for A and D windows (derived r9):
//   sign = Pt9 ^ j3*t0 ^ j0*t9 ^ pjc(j);  M[a=j3][b=j0] precomputed per thread.
#define SMASK(j) (((((j) & 8) ? (((j) & 1) ? M11 : M10) \
                              : (((j) & 1) ? M01 : M00))) ^ (pjc(j) << 31))

// ---- Plain pass: window bits SH+3..SH, gates QB..QB+3 (high->low local bit) ----
template<int SH, int QB>
__device__ __forceinline__ void passPlain(char* stb, const vf2 (*Gl)[4], int base) {
    vf2 aa[16];
    #pragma unroll
    for (int j = 0; j < 16; ++j)
        aa[j] = *(const vf2*)(stb + (base ^ (lswz(j << SH) << 3)));
    vf2 gA[4], gB[4];
    GL(gA, Gl, QB); GL(gB, Gl, QB + 1);
    APPLY16(3, gA); GL(gA, Gl, QB + 2);
    APPLY16(2, gB); GL(gB, Gl, QB + 3);
    APPLY16(1, gA);
    APPLY16(0, gB);
    #pragma unroll
    for (int j = 0; j < 16; ++j)
        *(vf2*)(stb + (base ^ (lswz(j << SH) << 3))) = aa[j];
}

// ---- Fused A pass: q0..3 of la, ring sign, q0..3 of lb (window bits 13..10) ----
__device__ __forceinline__ void passAA(char* stb, const vf2 (*Gla)[4], const vf2 (*Glb)[4],
                                       int base, unsigned M00, unsigned M01,
                                       unsigned M10, unsigned M11) {
    vf2 aa[16];
    #pragma unroll
    for (int j = 0; j < 16; ++j)
        aa[j] = *(const vf2*)(stb + (base ^ (lswz(j << 10) << 3)));
    vf2 gA[4], gB[4];
    GL(gA, Gla, 0); GL(gB, Gla, 1);
    APPLY16(3, gA); GL(gA, Gla, 2);
    APPLY16(2, gB); GL(gB, Gla, 3);
    APPLY16(1, gA); GL(gA, Glb, 0);
    APPLY16(0, gB); GL(gB, Glb, 1);
    #pragma unroll
    for (int j = 0; j < 16; ++j) aa[j] = sxor(aa[j], SMASK(j));
    APPLY16(3, gA); GL(gA, Glb, 2);
    APPLY16(2, gB); GL(gB, Glb, 3);
    APPLY16(1, gA);
    APPLY16(0, gB);
    #pragma unroll
    for (int j = 0; j < 16; ++j)
        *(vf2*)(stb + (base ^ (lswz(j << 10) << 3))) = aa[j];
}

// ---- Fused D pass: q12,13 of la, ring sign, q12,13 of lb (window bits 3..0) ----
__device__ __forceinline__ void passDD(char* stb, const vf2 (*Gla)[4], const vf2 (*Glb)[4],
                                       int base, unsigned M00, unsigned M01,
                                       unsigned M10, unsigned M11) {
    vf2 aa[16];
    #pragma unroll
    for (int j = 0; j < 16; ++j)
        aa[j] = *(const vf2*)(stb + (base ^ (j << 3)));
    vf2 gA[4], gB[4];
    GL(gA, Gla, 12); GL(gB, Gla, 13);
    APPLY16(1, gA); GL(gA, Glb, 12);
    APPLY16(0, gB); GL(gB, Glb, 13);
    #pragma unroll
    for (int j = 0; j < 16; ++j) aa[j] = sxor(aa[j], SMASK(j));
    APPLY16(1, gA);
    APPLY16(0, gB);
    #pragma unroll
    for (int j = 0; j < 16; ++j)
        *(vf2*)(stb + (base ^ (j << 3))) = aa[j];
}

__attribute__((amdgpu_flat_work_group_size(NTHREADS, NTHREADS),
               amdgpu_waves_per_eu(4, 4)))   // 16-wave block -> exactly 4 waves/EU, 128-VGPR budget
__global__ void pqc_kernel(
    const float* __restrict__ x,      // (B, 14)
    const float* __restrict__ theta,  // (252,)
    const float* __restrict__ lam,    // (70,)
    const float* __restrict__ w,      // (1, 2)
    float* __restrict__ out)          // (B, 2)
{
    __shared__ vf2 st[DIM];                    // 128 KiB state, layout L(i)
    __shared__ vf2 G[NLAYERS + 1][NQ][4];      // l=0: RZ*RY*RX; l>=1: (RZ*RY*RX)@RX_enc
    __shared__ float wsum[NTHREADS / 64];

    const int t = threadIdx.x;
    const int b = blockIdx.x;
    char* stb = (char*)st;

    // ---- Build all 84 fused gates (theta layout: 42*l + 3*q + c) ----
    if (t < (NLAYERS + 1) * NQ) {
        const int l = t / NQ, q = t % NQ;
        const float a0 = theta[3 * t + 0];
        const float a1 = theta[3 * t + 1];
        const float a2 = theta[3 * t + 2];
        const float cx = cosf(0.5f * a0), sx = sinf(0.5f * a0);
        const float cy = cosf(0.5f * a1), sy = sinf(0.5f * a1);
        const float cz = cosf(0.5f * a2), sz = sinf(0.5f * a2);
        const c32 m00 = {  cy * cx,  sy * sx };
        const c32 m01 = { -sy * cx, -cy * sx };
        const c32 m10 = {  sy * cx, -cy * sx };
        const c32 m11 = {  cy * cx, -sy * sx };
        c32 u00 = { cz * m00.x + sz * m00.y,  cz * m00.y - sz * m00.x };
        c32 u01 = { cz * m01.x + sz * m01.y,  cz * m01.y - sz * m01.x };
        c32 u10 = { cz * m10.x - sz * m10.y,  cz * m10.y + sz * m10.x };
        c32 u11 = { cz * m11.x - sz * m11.y,  cz * m11.y + sz * m11.x };
        if (l >= 1) {
            const float ang = x[b * NQ + q] * lam[(l - 1) * NQ + q];
            const float c = cosf(0.5f * ang), s = sinf(0.5f * ang);
            const c32 v00 = { u00.x * c + s * u01.y,  u00.y * c - s * u01.x };
            const c32 v01 = { u01.x * c + s * u00.y,  u01.y * c - s * u00.x };
            const c32 v10 = { u10.x * c + s * u11.y,  u10.y * c - s * u11.x };
            const c32 v11 = { u11.x * c + s * u10.y,  u11.y * c - s * u10.x };
            u00 = v00; u01 = v01; u10 = v10; u11 = v11;
        }
        G[l][q][0] = vf2{ u00.x, u00.y };
        G[l][q][1] = vf2{ u01.x, u01.y };
        G[l][q][2] = vf2{ u10.x, u10.y };
        G[l][q][3] = vf2{ u11.x, u11.y };
    }
    __syncthreads();

    // ---- Per-thread bases (byte offsets) ----
    const int baseA = lswz(t) << 3;                                  // i=(j<<10)|t
    const int baseB = lswz(((t >> 6) << 10) | (t & 63)) << 3;        // i=hi|(j<<6)|lo
    const int baseC = lswz(((t >> 2) << 6) | (t & 3)) << 3;          // i=hi|(j<<2)|lo
    const int baseD = lswz(t << 4) << 3;                             // i=(t<<4)|j
    // ---- Ring-sign words (shared by A and D windows) ----
    const unsigned Pt9 = (unsigned)(__popc(t & (t >> 1) & 0x1FF) & 1);
    const unsigned t9 = (t >> 9) & 1u, t0 = t & 1u;
    const unsigned M00 =  Pt9             << 31;
    const unsigned M01 = (Pt9 ^ t9)       << 31;   // j0=1
    const unsigned M10 = (Pt9 ^ t0)       << 31;   // j3=1
    const unsigned M11 = (Pt9 ^ t9 ^ t0)  << 31;

    // ===== Pass 1 (A window): analytic L0 state + sign1 + W1 q0..3 =====
    // i=(j<<10)|t: q0..3 <- j bits 3..0; q4..13 <- t bits 9..0.
    {
        const vf2 g4 = G[0][4][((t >> 9) & 1) ? 2 : 0];
        c32 pref = { g4.x, g4.y };
        #pragma unroll
        for (int qq = 5; qq <= 13; ++qq) {
            const vf2 g = G[0][qq][((t >> (13 - qq)) & 1) ? 2 : 0];
            pref = cmul(pref, c32{ g.x, g.y });
        }
        c32 p01p[4], p23[4];
        #pragma unroll
        for (int k = 0; k < 4; ++k) {
            const vf2 ga = G[0][0][(k >> 1) ? 2 : 0], gb = G[0][1][(k & 1) ? 2 : 0];
            const vf2 gc = G[0][2][(k >> 1) ? 2 : 0], gd = G[0][3][(k & 1) ? 2 : 0];
            p01p[k] = cmul(pref, cmul(c32{ ga.x, ga.y }, c32{ gb.x, gb.y }));
            p23[k]  = cmul(c32{ gc.x, gc.y }, c32{ gd.x, gd.y });
        }
        vf2 aa[16];
        #pragma unroll
        for (int j = 0; j < 16; ++j) {
            const c32 av = cmul(p01p[j >> 2], p23[j & 3]);
            aa[j] = sxor(vf2{ av.x, av.y }, SMASK(j));
        }
        vf2 gA[4], gB[4];
        GL(gA, G[1], 0); GL(gB, G[1], 1);
        APPLY16(3, gA); GL(gA, G[1], 2);
        APPLY16(2, gB); GL(gB, G[1], 3);
        APPLY16(1, gA);
        APPLY16(0, gB);
        #pragma unroll
        for (int j = 0; j < 16; ++j)
            *(vf2*)(stb + (baseA ^ (lswz(j << 10) << 3))) = aa[j];
    }
    __syncthreads();

    // ===== Fused 16-pass schedule =====
    passPlain<6, 4>(stb, G[1], baseB);                      __syncthreads();
    passPlain<2, 8>(stb, G[1], baseC);                      __syncthreads();
    passDD(stb, G[1], G[2], baseD, M00, M01, M10, M11);     __syncthreads();
    passPlain<2, 8>(stb, G[2], baseC);                      __syncthreads();
    passPlain<6, 4>(stb, G[2], baseB);                      __syncthreads();
    passAA(stb, G[2], G[3], baseA, M00, M01, M10, M11);     __syncthreads();
    passPlain<6, 4>(stb, G[3], baseB);                      __syncthreads();
    passPlain<2, 8>(stb, G[3], baseC);                      __syncthreads();
    passDD(stb, G[3], G[4], baseD, M00, M01, M10, M11);     __syncthreads();
    passPlain<2, 8>(stb, G[4], baseC);                      __syncthreads();
    passPlain<6, 4>(stb, G[4], baseB);                      __syncthreads();
    passAA(stb, G[4], G[5], baseA, M00, M01, M10, M11);     __syncthreads();
    passPlain<6, 4>(stb, G[5], baseB);                      __syncthreads();
    passPlain<2, 8>(stb, G[5], baseC);                      __syncthreads();

    // ===== Last pass (D window): W5 q12,13 + <Z^14> accumulate =====
    float se = 0.f, so = 0.f;
    {
        vf2 aa[16];
        #pragma unroll
        for (int j = 0; j < 16; ++j)
            aa[j] = *(const vf2*)(stb + (baseD ^ (j << 3)));
        vf2 gA[4], gB[4];
        GL(gA, G[5], 12); GL(gB, G[5], 13);
        APPLY16(1, gA);
        APPLY16(0, gB);
        #pragma unroll
        for (int j = 0; j < 16; ++j) {
            const float d = fmaf(aa[j].x, aa[j].x, aa[j].y * aa[j].y);
            if ((__popc(j) & 1) == 0) se += d; else so += d;
        }
    }

    // ---- Reduce + softmax ----
    float local = (__popc(t) & 1) ? (so - se) : (se - so);
    #pragma unroll
    for (int off = 32; off > 0; off >>= 1)
        local += __shfl_down(local, off, 64);
    if ((t & 63) == 0) wsum[t >> 6] = local;
    __syncthreads();
    if (t == 0) {
        float v = 0.0f;
        #pragma unroll
        for (int i = 0; i < NTHREADS / 64; ++i) v += wsum[i];
        const float BETA = 1.0f;
        const float l0 = v * w[0] * BETA, l1 = v * w[1] * BETA;
        const float m  = fmaxf(l0, l1);
        const float e0 = __expf(l0 - m), e1 = __expf(l1 - m);
        const float inv = 1.0f / (e0 + e1);
        out[2 * b + 0] = e0 * inv;
        out[2 * b + 1] = e1 * inv;
    }
}

extern "C" void kernel_launch(void* const* d_in, const int* in_sizes, int n_in,
                              void* d_out, int out_size, void* d_ws, size_t ws_size,
                              hipStream_t stream) {
    const float* x     = (const float*)d_in[0];
    const float* theta = (const float*)d_in[1];
    const float* lam   = (const float*)d_in[2];
    const float* w     = (const float*)d_in[3];
    float* out = (float*)d_out;
    const int batch = in_sizes[0] / NQ;   // 2048
    pqc_kernel<<<batch, NTHREADS, 0, stream>>>(x, theta, lam, w, out);
}

// Round 10
// 291.127 us; speedup vs baseline: 1.3686x; 1.3686x over previous
//
#include <hip/hip_runtime.h>
#include <math.h>

#define NQ        14
#define DIM       16384          // 2^14
#define NLAYERS   5
#define NTHREADS  512            // 32 amps/thread

typedef float vf2 __attribute__((ext_vector_type(2)));
struct c32 { float x, y; };

// GF(2)-LINEAR layout (r6-r8, verified): pass address = base ^ compile-time const.
__host__ __device__ constexpr int lswz(int i) {
    return i ^ ((i >> 4) & 15) ^ ((i >> 8) & 15) ^ ((i >> 12) & 3);
}
__host__ __device__ constexpr unsigned sjc(int j) {
    return (((j >> 4) & (j >> 3)) ^ ((j >> 3) & (j >> 2)) ^
            ((j >> 2) & (j >> 1)) ^ ((j >> 1) & j)) & 1u;
}
__host__ __device__ constexpr unsigned pjc(int j) {
    return (((j >> 3) & (j >> 2)) ^ ((j >> 2) & (j >> 1)) ^ ((j >> 1) & j)) & 1u;
}

__device__ __forceinline__ c32 cmul(c32 a, c32 b) {
    return { a.x * b.x - a.y * b.y, a.x * b.y + a.y * b.x };
}
__device__ __forceinline__ vf2 sxor(vf2 v, unsigned m) {
    return vf2{ __uint_as_float(__float_as_uint(v.x) ^ m),
                __uint_as_float(__float_as_uint(v.y) ^ m) };
}

// Complex mult z' = g*z in 2 VOP3P (instr pattern proven in r7's bf).
__device__ __forceinline__ vf2 cmulv(vf2 g, vf2 z) {
    vf2 o;
    asm("v_pk_mul_f32 %0, %1, %2 op_sel:[1,1] op_sel_hi:[1,0] neg_lo:[0,1] neg_hi:[0,0]\n\t"
        "v_pk_fma_f32 %0, %1, %2, %0 op_sel:[0,0,0] op_sel_hi:[0,1,1]"
        : "=&v"(o) : "v"(g), "v"(z));
    return o;
}

// REAL rotation butterfly in 4 VOP3P: r = (cb, sb);
//   B0 = cb*A0 - sb*A1 ; B1 = sb*A0 + cb*A1
__device__ __forceinline__ void bfr(vf2 r, vf2& A0, vf2& A1) {
    vf2 b0, b1;
    asm("v_pk_mul_f32 %0, %2, %3 op_sel:[0,0] op_sel_hi:[0,1]\n\t"
        "v_pk_fma_f32 %0, %2, %4, %0 op_sel:[1,0,0] op_sel_hi:[1,1,1] neg_lo:[1,0,0] neg_hi:[1,0,0]\n\t"
        "v_pk_mul_f32 %1, %2, %3 op_sel:[1,0] op_sel_hi:[1,1]\n\t"
        "v_pk_fma_f32 %1, %2, %4, %1 op_sel:[0,0,0] op_sel_hi:[0,1,1]"
        : "=&v"(b0), "=&v"(b1)
        : "v"(r), "v"(A0), "v"(A1));
    A0 = b0; A1 = b1;
}

#define APPLY32R(K, RV) { const vf2 rv_ = (RV); _Pragma("unroll") \
    for (int mm = 0; mm < 16; ++mm) { \
        const int r0 = ((mm >> (K)) << ((K) + 1)) | (mm & ((1 << (K)) - 1)); \
        bfr(rv_, a[r0], a[r0 | (1 << (K))]); } }
#define APPLY16R(K, RV) { const vf2 rv_ = (RV); _Pragma("unroll") \
    for (int mm = 0; mm < 8; ++mm) { \
        const int r0 = ((mm >> (K)) << ((K) + 1)) | (mm & ((1 << (K)) - 1)); \
        bfr(rv_, aa[r0], aa[r0 | (1 << (K))]); } }

// Ring-sign masks (r8, verified).
#define AMASK(j) ((((j) & 1) ? (((j) & 16) ? M11 : M10) : (((j) & 16) ? M01 : M00)) \
                  ^ (sjc(j) << 31))
#define CMASK(v, j) ((((v)) ? (((j) & 8) ? C11 : C10) : (((j) & 8) ? C01 : C00)) \
                     ^ (((pjc(j) ^ ((j) & (v) & 1)) & 1u) << 31))

// ---- B pass: load, phase table, 5 real gates (q5..9), store ----
__device__ __forceinline__ void passB(char* stb, const vf2* GrL, const vf2* Tk, int base2) {
    vf2 a[32];
    #pragma unroll
    for (int j = 0; j < 32; ++j)
        a[j] = *(const vf2*)(stb + (base2 ^ (lswz(j << 4) << 3)));
    #pragma unroll
    for (int j = 0; j < 32; ++j) a[j] = cmulv(Tk[j], a[j]);
    APPLY32R(4, GrL[5]); APPLY32R(3, GrL[6]); APPLY32R(2, GrL[7]);
    APPLY32R(1, GrL[8]); APPLY32R(0, GrL[9]);
    #pragma unroll
    for (int j = 0; j < 32; ++j)
        *(vf2*)(stb + (base2 ^ (lswz(j << 4) << 3))) = a[j];
}

// ---- Fused A pass: Ta, gates la q0..4, ring sign, Tb, gates lb q0..4 ----
__device__ __forceinline__ void passAA(char* stb, const vf2* GrA, const vf2* GrB,
                                       const vf2* Ta, const vf2* Tb, int base1,
                                       unsigned M00, unsigned M01, unsigned M10, unsigned M11) {
    vf2 a[32];
    #pragma unroll
    for (int j = 0; j < 32; ++j)
        a[j] = *(const vf2*)(stb + (base1 ^ (lswz(j << 9) << 3)));
    #pragma unroll
    for (int j = 0; j < 32; ++j) a[j] = cmulv(Ta[j], a[j]);
    APPLY32R(4, GrA[0]); APPLY32R(3, GrA[1]); APPLY32R(2, GrA[2]);
    APPLY32R(1, GrA[3]); APPLY32R(0, GrA[4]);
    #pragma unroll
    for (int j = 0; j < 32; ++j) a[j] = cmulv(Tb[j], sxor(a[j], AMASK(j)));
    APPLY32R(4, GrB[0]); APPLY32R(3, GrB[1]); APPLY32R(2, GrB[2]);
    APPLY32R(1, GrB[3]); APPLY32R(0, GrB[4]);
    #pragma unroll
    for (int j = 0; j < 32; ++j)
        *(vf2*)(stb + (base1 ^ (lswz(j << 9) << 3))) = a[j];
}

// ---- Fused C pass: Ta, gates la q10..13, ring sign, Tb, gates lb q10..13 ----
__device__ __forceinline__ void passCC(char* stb, const vf2* GrA, const vf2* GrB,
                                       const vf2* Ta, const vf2* Tb, int base3,
                                       unsigned C00, unsigned C01, unsigned C10, unsigned C11) {
    #pragma unroll
    for (int v = 0; v < 2; ++v) {
        const int bb = base3 ^ (lswz(v << 13) << 3);
        vf2 aa[16];
        #pragma unroll
        for (int j = 0; j < 16; ++j)
            aa[j] = *(const vf2*)(stb + (bb ^ (j << 3)));
        #pragma unroll
        for (int j = 0; j < 16; ++j) aa[j] = cmulv(Ta[j], aa[j]);
        APPLY16R(3, GrA[10]); APPLY16R(2, GrA[11]); APPLY16R(1, GrA[12]); APPLY16R(0, GrA[13]);
        #pragma unroll
        for (int j = 0; j < 16; ++j) aa[j] = cmulv(Tb[j], sxor(aa[j], CMASK(v, j)));
        APPLY16R(3, GrB[10]); APPLY16R(2, GrB[11]); APPLY16R(1, GrB[12]); APPLY16R(0, GrB[13]);
        #pragma unroll
        for (int j = 0; j < 16; ++j)
            *(vf2*)(stb + (bb ^ (j << 3))) = aa[j];
    }
}

// ---- Last C pass: Tk, gates l5 q10..13, |amp|^2 accumulate ----
__device__ __forceinline__ void passCLast(char* stb, const vf2* GrL, const vf2* Tk,
                                          int base3, float& se, float& so) {
    #pragma unroll
    for (int v = 0; v < 2; ++v) {
        const int bb = base3 ^ (lswz(v << 13) << 3);
        vf2 aa[16];
        #pragma unroll
        for (int j = 0; j < 16; ++j)
            aa[j] = *(const vf2*)(stb + (bb ^ (j << 3)));
        #pragma unroll
        for (int j = 0; j < 16; ++j) aa[j] = cmulv(Tk[j], aa[j]);
        APPLY16R(3, GrL[10]); APPLY16R(2, GrL[11]); APPLY16R(1, GrL[12]); APPLY16R(0, GrL[13]);
        #pragma unroll
        for (int j = 0; j < 16; ++j) {
            const float d = fmaf(aa[j].x, aa[j].x, aa[j].y * aa[j].y);
            if (((v ^ __popc(j)) & 1) == 0) se += d; else so += d;
        }
    }
}

__attribute__((amdgpu_flat_work_group_size(NTHREADS, NTHREADS),
               amdgpu_waves_per_eu(2, 2)))
__global__ void pqc_kernel(
    const float* __restrict__ x,      // (B, 14)
    const float* __restrict__ theta,  // (252,)
    const float* __restrict__ lam,    // (70,)
    const float* __restrict__ w,      // (1, 2)
    float* __restrict__ out)          // (B, 2)
{
    __shared__ vf2 st[DIM];                    // 128 KiB state, layout L(i)
    __shared__ vf2 Gr[NLAYERS + 1][NQ];        // (cos b/2, sin b/2)
    __shared__ vf2 Gang[NLAYERS + 1][NQ];      // (a/2, c/2)
    __shared__ vf2 G0c[NQ][2];                 // layer-0 (u00, u10)
    __shared__ vf2 F0[5][2];                   // init factors q0..4 incl DR_A1
    __shared__ vf2 T[15][32];                  // boundary phase tables
    __shared__ float wsum[NTHREADS / 64];

    const int t = threadIdx.x;
    const int b = blockIdx.x;
    char* stb = (char*)st;

    // ---- Build: U (complex, enc fused) -> ZYZ decomposition ----
    if (t < (NLAYERS + 1) * NQ) {
        const int l = t / NQ, q = t % NQ;
        const float a0 = theta[3 * t + 0];
        const float a1 = theta[3 * t + 1];
        const float a2t = theta[3 * t + 2];
        const float cx = cosf(0.5f * a0), sx = sinf(0.5f * a0);
        const float cy = cosf(0.5f * a1), sy = sinf(0.5f * a1);
        const float cz = cosf(0.5f * a2t), sz = sinf(0.5f * a2t);
        const c32 m00 = {  cy * cx,  sy * sx };
        const c32 m01 = { -sy * cx, -cy * sx };
        const c32 m10 = {  sy * cx, -cy * sx };
        c32 u00 = { cz * m00.x + sz * m00.y,  cz * m00.y - sz * m00.x };
        c32 u01 = { cz * m01.x + sz * m01.y,  cz * m01.y - sz * m01.x };
        c32 u10 = { cz * m10.x - sz * m10.y,  cz * m10.y + sz * m10.x };
        if (l >= 1) {
            const float ang = x[b * NQ + q] * lam[(l - 1) * NQ + q];
            const float c = cosf(0.5f * ang), s = sinf(0.5f * ang);
            const c32 u11 = { u00.x, -u00.y };                    // SU(2)
            const c32 v00 = { u00.x * c + s * u01.y,  u00.y * c - s * u01.x };
            const c32 v10 = { u10.x * c + s * u11.y,  u10.y * c - s * u11.x };
            u00 = v00; u10 = v10;
        }
        if (l == 0) {
            G0c[q][0] = vf2{ u00.x, u00.y };
            G0c[q][1] = vf2{ u10.x, u10.y };
        }
        const float cb = sqrtf(u00.x * u00.x + u00.y * u00.y);
        const float sb = sqrtf(u10.x * u10.x + u10.y * u10.y);
        const float inv = rsqrtf(fmaxf(cb * cb + sb * sb, 1e-30f));
        const float p  = atan2f(u00.y, u00.x);
        const float qq = atan2f(u10.y, u10.x);
        Gr[l][q]   = vf2{ cb * inv, sb * inv };
        Gang[l][q] = vf2{ 0.5f * (qq - p), -0.5f * (p + qq) };    // (a/2, c/2)
    }
    __syncthreads();

    // ---- Boundary phase tables T[1..14]; init factors F0 ----
    if (t < 448) {
        const int k = 1 + (t >> 5), j = t & 31;
        const int r = k % 6;
        const int win = (r == 0 || r == 5) ? 0 : ((r == 1 || r == 4) ? 1 : 2);
        if (win != 2 || j < 16) {
            const int lc = 1 + k / 3;
            const int lp = (k >= 3) ? lc - 1 : 0;
            const int nb = (win == 2) ? 4 : 5;
            float th = 0.f;
            for (int m = 0; m < nb; ++m) {
                const int q = (win == 0) ? (4 - m) : (win == 1) ? (9 - m) : (13 - m);
                float ww = Gang[lc][q].y;
                if (lp) ww += Gang[lp][q].x;
                th += ((j >> m) & 1) ? ww : -ww;
            }
            float sn, cn;
            __sincosf(th, &sn, &cn);
            T[k][j] = vf2{ cn, sn };
        }
    } else if (t < 458) {
        const int u = t - 448, q = u >> 1, be = u & 1;
        const float c2 = Gang[1][q].y;
        const float ph = be ? c2 : -c2;
        float sn, cn;
        __sincosf(ph, &sn, &cn);
        const vf2 g = G0c[q][be];
        const c32 f = cmul(c32{ g.x, g.y }, c32{ cn, sn });
        F0[q][be] = vf2{ f.x, f.y };
    }
    __syncthreads();

    // ---- Bases & ring-sign words (r8, verified) ----
    const int base1 = lswz(t) << 3;
    const int base2 = lswz(((t & 0x1F0) << 5) | (t & 15)) << 3;
    const int base3 = lswz(t << 4) << 3;
    const unsigned Pp  = (unsigned)(__popc(t & (t >> 1) & 0xFF) & 1);
    const unsigned t8 = (t >> 8) & 1u, tb0 = t & 1u;
    const unsigned M00 =  Pp              << 31;
    const unsigned M10 = (Pp ^ t8)        << 31;
    const unsigned M01 = (Pp ^ tb0)       << 31;
    const unsigned M11 = (Pp ^ t8 ^ tb0)  << 31;
    const unsigned C00 =  Pp              << 31;
    const unsigned C01 = (Pp ^ tb0)       << 31;
    const unsigned C10 = (Pp ^ t8)        << 31;
    const unsigned C11 = (Pp ^ t8 ^ tb0)  << 31;

    // ===== P1 (A window): analytic L0 (+DR_A1 via F0) + S1 + real A1 gates =====
    {
        c32 pref = { G0c[5][(t >> 8) & 1].x, G0c[5][(t >> 8) & 1].y };
        #pragma unroll
        for (int qq = 6; qq <= 13; ++qq) {
            const vf2 g = G0c[qq][(t >> (13 - qq)) & 1];
            pref = cmul(pref, c32{ g.x, g.y });
        }
        c32 p01p[4], p234[8];
        #pragma unroll
        for (int k = 0; k < 4; ++k) {
            const vf2 ga = F0[0][k >> 1], gb = F0[1][k & 1];
            p01p[k] = cmul(pref, cmul(c32{ ga.x, ga.y }, c32{ gb.x, gb.y }));
        }
        #pragma unroll
        for (int m = 0; m < 8; ++m) {
            const vf2 g2 = F0[2][m >> 2], g3 = F0[3][(m >> 1) & 1], g4 = F0[4][m & 1];
            p234[m] = cmul(cmul(c32{ g2.x, g2.y }, c32{ g3.x, g3.y }), c32{ g4.x, g4.y });
        }
        vf2 a[32];
        #pragma unroll
        for (int j = 0; j < 32; ++j) {
            const c32 av = cmul(p01p[j >> 3], p234[j & 7]);
            a[j] = sxor(vf2{ av.x, av.y }, AMASK(j));
        }
        APPLY32R(4, Gr[1][0]); APPLY32R(3, Gr[1][1]); APPLY32R(2, Gr[1][2]);
        APPLY32R(1, Gr[1][3]); APPLY32R(0, Gr[1][4]);
        #pragma unroll
        for (int j = 0; j < 32; ++j)
            *(vf2*)(stb + (base1 ^ (lswz(j << 9) << 3))) = a[j];
    }
    __syncthreads();

    // ===== Fused 11-pass schedule with deferred-diagonal tables =====
    passB(stb, Gr[1], T[1], base2);                                        __syncthreads();
    passCC(stb, Gr[1], Gr[2], T[2], T[3], base3, C00, C01, C10, C11);      __syncthreads();
    passB(stb, Gr[2], T[4], base2);                                        __syncthreads();
    passAA(stb, Gr[2], Gr[3], T[5], T[6], base1, M00, M01, M10, M11);      __syncthreads();
    passB(stb, Gr[3], T[7], base2);                                        __syncthreads();
    passCC(stb, Gr[3], Gr[4], T[8], T[9], base3, C00, C01, C10, C11);      __syncthreads();
    passB(stb, Gr[4], T[10], base2);                                       __syncthreads();
    passAA(stb, Gr[4], Gr[5], T[11], T[12], base1, M00, M01, M10, M11);    __syncthreads();
    passB(stb, Gr[5], T[13], base2);                                       __syncthreads();
    float se = 0.f, so = 0.f;
    passCLast(stb, Gr[5], T[14], base3, se, so);

    // ---- Reduce + softmax ----
    float local = (__popc(t) & 1) ? (so - se) : (se - so);
    #pragma unroll
    for (int off = 32; off > 0; off >>= 1)
        local += __shfl_down(local, off, 64);
    if ((t & 63) == 0) wsum[t >> 6] = local;
    __syncthreads();
    if (t == 0) {
        float v = 0.0f;
        #pragma unroll
        for (int i = 0; i < NTHREADS / 64; ++i) v += wsum[i];
        const float BETA = 1.0f;
        const float l0 = v * w[0] * BETA, l1 = v * w[1] * BETA;
        const float m  = fmaxf(l0, l1);
        const float e0 = __expf(l0 - m), e1 = __expf(l1 - m);
        const float inv = 1.0f / (e0 + e1);
        out[2 * b + 0] = e0 * inv;
        out[2 * b + 1] = e1 * inv;
    }
}

extern "C" void kernel_launch(void* const* d_in, const int* in_sizes, int n_in,
                              void* d_out, int out_size, void* d_ws, size_t ws_size,
                              hipStream_t stream) {
    const float* x     = (const float*)d_in[0];
    const float* theta = (const float*)d_in[1];
    const float* lam   = (const float*)d_in[2];
    const float* w     = (const float*)d_in[3];
    float* out = (float*)d_out;
    const int batch = in_sizes[0] / NQ;   // 2048
    pqc_kernel<<<batch, NTHREADS, 0, stream>>>(x, theta, lam, w, out);
}

// Round 11
// 263.239 us; speedup vs baseline: 1.5137x; 1.1059x over previous
//
#include <hip/hip_runtime.h>
#include <hip/hip_fp16.h>
#include <math.h>

#define NQ        14
#define DIM       16384          // 2^14
#define NLAYERS   5
#define NTHREADS  512            // 32 amps/thread

typedef float vf2 __attribute__((ext_vector_type(2)));
struct c32 { float x, y; };

// GF(2)-LINEAR layout for 4B (half2) elements: sigma from bits>=5 into bits 4:0.
// L5(a^b)=L5(a)^L5(b). Hand-verified <=2-way bank conflicts (free) for A/B/C/init
// patterns at 64 lanes x 32 banks.
__host__ __device__ constexpr int lswz5(int i) {
    return i ^ ((i >> 5) & 31) ^ ((i >> 10) & 15);
}
__host__ __device__ constexpr unsigned sjc(int j) {   // 5-bit adjacent-pair parity
    return (((j >> 4) & (j >> 3)) ^ ((j >> 3) & (j >> 2)) ^
            ((j >> 2) & (j >> 1)) ^ ((j >> 1) & j)) & 1u;
}
__host__ __device__ constexpr unsigned pjc(int j) {   // 4-bit adjacent-pair parity
    return (((j >> 3) & (j >> 2)) ^ ((j >> 2) & (j >> 1)) ^ ((j >> 1) & j)) & 1u;
}

__device__ __forceinline__ c32 cmul(c32 a, c32 b) {
    return { a.x * b.x - a.y * b.y, a.x * b.y + a.y * b.x };
}
__device__ __forceinline__ vf2 sxor(vf2 v, unsigned m) {
    return vf2{ __uint_as_float(__float_as_uint(v.x) ^ m),
                __uint_as_float(__float_as_uint(v.y) ^ m) };
}

// fp16 state pack/unpack (RTN for unbiased rounding).
__device__ __forceinline__ unsigned pk16(vf2 v) {
    __half2 h = __float22half2_rn(float2{ v.x, v.y });
    return *reinterpret_cast<unsigned*>(&h);
}
__device__ __forceinline__ vf2 up16(unsigned u) {
    __half2 h = *reinterpret_cast<__half2*>(&u);
    float2 f = __half22float2(h);
    return vf2{ f.x, f.y };
}

// Complex mult z' = g*z in 2 VOP3P (r7-proven pattern).
__device__ __forceinline__ vf2 cmulv(vf2 g, vf2 z) {
    vf2 o;
    asm("v_pk_mul_f32 %0, %1, %2 op_sel:[1,1] op_sel_hi:[1,0] neg_lo:[0,1] neg_hi:[0,0]\n\t"
        "v_pk_fma_f32 %0, %1, %2, %0 op_sel:[0,0,0] op_sel_hi:[0,1,1]"
        : "=&v"(o) : "v"(g), "v"(z));
    return o;
}

// REAL rotation butterfly in 4 VOP3P (r10-proven).
__device__ __forceinline__ void bfr(vf2 r, vf2& A0, vf2& A1) {
    vf2 b0, b1;
    asm("v_pk_mul_f32 %0, %2, %3 op_sel:[0,0] op_sel_hi:[0,1]\n\t"
        "v_pk_fma_f32 %0, %2, %4, %0 op_sel:[1,0,0] op_sel_hi:[1,1,1] neg_lo:[1,0,0] neg_hi:[1,0,0]\n\t"
        "v_pk_mul_f32 %1, %2, %3 op_sel:[1,0] op_sel_hi:[1,1]\n\t"
        "v_pk_fma_f32 %1, %2, %4, %1 op_sel:[0,0,0] op_sel_hi:[0,1,1]"
        : "=&v"(b0), "=&v"(b1)
        : "v"(r), "v"(A0), "v"(A1));
    A0 = b0; A1 = b1;
}

#define APPLY32R(K, RV) { const vf2 rv_ = (RV); _Pragma("unroll") \
    for (int mm = 0; mm < 16; ++mm) { \
        const int r0 = ((mm >> (K)) << ((K) + 1)) | (mm & ((1 << (K)) - 1)); \
        bfr(rv_, a[r0], a[r0 | (1 << (K))]); } }
#define APPLY16R(K, RV) { const vf2 rv_ = (RV); _Pragma("unroll") \
    for (int mm = 0; mm < 8; ++mm) { \
        const int r0 = ((mm >> (K)) << ((K) + 1)) | (mm & ((1 << (K)) - 1)); \
        bfr(rv_, aa[r0], aa[r0 | (1 << (K))]); } }

// Ring-sign masks (r8/r10, verified).
#define AMASK(j) ((((j) & 1) ? (((j) & 16) ? M11 : M10) : (((j) & 16) ? M01 : M00)) \
                  ^ (sjc(j) << 31))
#define CMASK(v, j) ((((v)) ? (((j) & 8) ? C11 : C10) : (((j) & 8) ? C01 : C00)) \
                     ^ (((pjc(j) ^ ((j) & (v) & 1)) & 1u) << 31))

// ---- B pass: load, phase table, 5 real gates (q5..9), store ----
__device__ __forceinline__ void passB(char* stb, const vf2* GrL, const vf2* Tk, int base2) {
    vf2 a[32];
    #pragma unroll
    for (int j = 0; j < 32; ++j)
        a[j] = up16(*(const unsigned*)(stb + (base2 ^ (lswz5(j << 4) << 2))));
    #pragma unroll
    for (int j = 0; j < 32; ++j) a[j] = cmulv(Tk[j], a[j]);
    APPLY32R(4, GrL[5]); APPLY32R(3, GrL[6]); APPLY32R(2, GrL[7]);
    APPLY32R(1, GrL[8]); APPLY32R(0, GrL[9]);
    #pragma unroll
    for (int j = 0; j < 32; ++j)
        *(unsigned*)(stb + (base2 ^ (lswz5(j << 4) << 2))) = pk16(a[j]);
}

// ---- Fused A pass: Ta, gates la q0..4, ring sign, Tb, gates lb q0..4 ----
__device__ __forceinline__ void passAA(char* stb, const vf2* GrA, const vf2* GrB,
                                       const vf2* Ta, const vf2* Tb, int base1,
                                       unsigned M00, unsigned M01, unsigned M10, unsigned M11) {
    vf2 a[32];
    #pragma unroll
    for (int j = 0; j < 32; ++j)
        a[j] = up16(*(const unsigned*)(stb + (base1 ^ (lswz5(j << 9) << 2))));
    #pragma unroll
    for (int j = 0; j < 32; ++j) a[j] = cmulv(Ta[j], a[j]);
    APPLY32R(4, GrA[0]); APPLY32R(3, GrA[1]); APPLY32R(2, GrA[2]);
    APPLY32R(1, GrA[3]); APPLY32R(0, GrA[4]);
    #pragma unroll
    for (int j = 0; j < 32; ++j) a[j] = cmulv(Tb[j], sxor(a[j], AMASK(j)));
    APPLY32R(4, GrB[0]); APPLY32R(3, GrB[1]); APPLY32R(2, GrB[2]);
    APPLY32R(1, GrB[3]); APPLY32R(0, GrB[4]);
    #pragma unroll
    for (int j = 0; j < 32; ++j)
        *(unsigned*)(stb + (base1 ^ (lswz5(j << 9) << 2))) = pk16(a[j]);
}

// ---- Fused C pass: Ta, gates la q10..13, ring sign, Tb, gates lb q10..13 ----
__device__ __forceinline__ void passCC(char* stb, const vf2* GrA, const vf2* GrB,
                                       const vf2* Ta, const vf2* Tb, int base3,
                                       unsigned C00, unsigned C01, unsigned C10, unsigned C11) {
    #pragma unroll
    for (int v = 0; v < 2; ++v) {
        const int bb = base3 ^ (lswz5(v << 13) << 2);
        vf2 aa[16];
        #pragma unroll
        for (int j = 0; j < 16; ++j)
            aa[j] = up16(*(const unsigned*)(stb + (bb ^ (j << 2))));
        #pragma unroll
        for (int j = 0; j < 16; ++j) aa[j] = cmulv(Ta[j], aa[j]);
        APPLY16R(3, GrA[10]); APPLY16R(2, GrA[11]); APPLY16R(1, GrA[12]); APPLY16R(0, GrA[13]);
        #pragma unroll
        for (int j = 0; j < 16; ++j) aa[j] = cmulv(Tb[j], sxor(aa[j], CMASK(v, j)));
        APPLY16R(3, GrB[10]); APPLY16R(2, GrB[11]); APPLY16R(1, GrB[12]); APPLY16R(0, GrB[13]);
        #pragma unroll
        for (int j = 0; j < 16; ++j)
            *(unsigned*)(stb + (bb ^ (j << 2))) = pk16(aa[j]);
    }
}

// ---- Last C pass: Tk, gates l5 q10..13, |amp|^2 accumulate ----
__device__ __forceinline__ void passCLast(char* stb, const vf2* GrL, const vf2* Tk,
                                          int base3, float& se, float& so) {
    #pragma unroll
    for (int v = 0; v < 2; ++v) {
        const int bb = base3 ^ (lswz5(v << 13) << 2);
        vf2 aa[16];
        #pragma unroll
        for (int j = 0; j < 16; ++j)
            aa[j] = up16(*(const unsigned*)(stb + (bb ^ (j << 2))));
        #pragma unroll
        for (int j = 0; j < 16; ++j) aa[j] = cmulv(Tk[j], aa[j]);
        APPLY16R(3, GrL[10]); APPLY16R(2, GrL[11]); APPLY16R(1, GrL[12]); APPLY16R(0, GrL[13]);
        #pragma unroll
        for (int j = 0; j < 16; ++j) {
            const float d = fmaf(aa[j].x, aa[j].x, aa[j].y * aa[j].y);
            if (((v ^ __popc(j)) & 1) == 0) se += d; else so += d;
        }
    }
}

__attribute__((amdgpu_flat_work_group_size(NTHREADS, NTHREADS),
               amdgpu_waves_per_eu(4, 4)))   // 2 blocks/CU (70KB LDS) -> 4 waves/EU, 128-VGPR budget
__global__ void pqc_kernel(
    const float* __restrict__ x,      // (B, 14)
    const float* __restrict__ theta,  // (252,)
    const float* __restrict__ lam,    // (70,)
    const float* __restrict__ w,      // (1, 2)
    float* __restrict__ out)          // (B, 2)
{
    __shared__ unsigned sth[DIM];              // 64 KiB fp16x2 state, layout L5(i)
    __shared__ vf2 Gr[NLAYERS + 1][NQ];        // (cos b/2, sin b/2)
    __shared__ vf2 Gang[NLAYERS + 1][NQ];      // (a/2, c/2)
    __shared__ vf2 G0c[NQ][2];                 // layer-0 (u00, u10)
    __shared__ vf2 F0[5][2];                   // init factors q0..4 incl DR_A1
    __shared__ vf2 T[15][32];                  // boundary phase tables
    __shared__ float wsum[NTHREADS / 64];

    const int t = threadIdx.x;
    const int b = blockIdx.x;
    char* stb = (char*)sth;

    // ---- Build: U (complex, enc fused) -> ZYZ decomposition ----
    if (t < (NLAYERS + 1) * NQ) {
        const int l = t / NQ, q = t % NQ;
        const float a0 = theta[3 * t + 0];
        const float a1 = theta[3 * t + 1];
        const float a2t = theta[3 * t + 2];
        const float cx = cosf(0.5f * a0), sx = sinf(0.5f * a0);
        const float cy = cosf(0.5f * a1), sy = sinf(0.5f * a1);
        const float cz = cosf(0.5f * a2t), sz = sinf(0.5f * a2t);
        const c32 m00 = {  cy * cx,  sy * sx };
        const c32 m01 = { -sy * cx, -cy * sx };
        const c32 m10 = {  sy * cx, -cy * sx };
        c32 u00 = { cz * m00.x + sz * m00.y,  cz * m00.y - sz * m00.x };
        c32 u01 = { cz * m01.x + sz * m01.y,  cz * m01.y - sz * m01.x };
        c32 u10 = { cz * m10.x - sz * m10.y,  cz * m10.y + sz * m10.x };
        if (l >= 1) {
            const float ang = x[b * NQ + q] * lam[(l - 1) * NQ + q];
            const float c = cosf(0.5f * ang), s = sinf(0.5f * ang);
            const c32 u11 = { u00.x, -u00.y };                    // SU(2)
            const c32 v00 = { u00.x * c + s * u01.y,  u00.y * c - s * u01.x };
            const c32 v10 = { u10.x * c + s * u11.y,  u10.y * c - s * u11.x };
            u00 = v00; u10 = v10;
        }
        if (l == 0) {
            G0c[q][0] = vf2{ u00.x, u00.y };
            G0c[q][1] = vf2{ u10.x, u10.y };
        }
        const float cb = sqrtf(u00.x * u00.x + u00.y * u00.y);
        const float sb = sqrtf(u10.x * u10.x + u10.y * u10.y);
        const float inv = rsqrtf(fmaxf(cb * cb + sb * sb, 1e-30f));
        const float p  = atan2f(u00.y, u00.x);
        const float qq = atan2f(u10.y, u10.x);
        Gr[l][q]   = vf2{ cb * inv, sb * inv };
        Gang[l][q] = vf2{ 0.5f * (qq - p), -0.5f * (p + qq) };    // (a/2, c/2)
    }
    __syncthreads();

    // ---- Boundary phase tables T[1..14]; init factors F0 ----
    if (t < 448) {
        const int k = 1 + (t >> 5), j = t & 31;
        const int r = k % 6;
        const int win = (r == 0 || r == 5) ? 0 : ((r == 1 || r == 4) ? 1 : 2);
        if (win != 2 || j < 16) {
            const int lc = 1 + k / 3;
            const int lp = (k >= 3) ? lc - 1 : 0;
            const int nb = (win == 2) ? 4 : 5;
            float th = 0.f;
            for (int m = 0; m < nb; ++m) {
                const int q = (win == 0) ? (4 - m) : (win == 1) ? (9 - m) : (13 - m);
                float ww = Gang[lc][q].y;
                if (lp) ww += Gang[lp][q].x;
                th += ((j >> m) & 1) ? ww : -ww;
            }
            float sn, cn;
            __sincosf(th, &sn, &cn);
            T[k][j] = vf2{ cn, sn };
        }
    } else if (t < 458) {
        const int u = t - 448, q = u >> 1, be = u & 1;
        const float c2 = Gang[1][q].y;
        const float ph = be ? c2 : -c2;
        float sn, cn;
        __sincosf(ph, &sn, &cn);
        const vf2 g = G0c[q][be];
        const c32 f = cmul(c32{ g.x, g.y }, c32{ cn, sn });
        F0[q][be] = vf2{ f.x, f.y };
    }
    __syncthreads();

    // ---- Bases (byte offsets, 4B elements) & ring-sign words ----
    const int base1 = lswz5(t) << 2;
    const int base2 = lswz5(((t & 0x1F0) << 5) | (t & 15)) << 2;
    const int base3 = lswz5(t << 4) << 2;
    const unsigned Pp  = (unsigned)(__popc(t & (t >> 1) & 0xFF) & 1);
    const unsigned t8 = (t >> 8) & 1u, tb0 = t & 1u;
    const unsigned M00 =  Pp              << 31;
    const unsigned M10 = (Pp ^ t8)        << 31;
    const unsigned M01 = (Pp ^ tb0)       << 31;
    const unsigned M11 = (Pp ^ t8 ^ tb0)  << 31;
    const unsigned C00 =  Pp              << 31;
    const unsigned C01 = (Pp ^ tb0)       << 31;
    const unsigned C10 = (Pp ^ t8)        << 31;
    const unsigned C11 = (Pp ^ t8 ^ tb0)  << 31;

    // ===== P1 (A window): analytic L0 (+DR_A1 via F0) + S1 + real A1 gates =====
    {
        c32 pref = { G0c[5][(t >> 8) & 1].x, G0c[5][(t >> 8) & 1].y };
        #pragma unroll
        for (int qq = 6; qq <= 13; ++qq) {
            const vf2 g = G0c[qq][(t >> (13 - qq)) & 1];
            pref = cmul(pref, c32{ g.x, g.y });
        }
        c32 p01p[4], p234[8];
        #pragma unroll
        for (int k = 0; k < 4; ++k) {
            const vf2 ga = F0[0][k >> 1], gb = F0[1][k & 1];
            p01p[k] = cmul(pref, cmul(c32{ ga.x, ga.y }, c32{ gb.x, gb.y }));
        }
        #pragma unroll
        for (int m = 0; m < 8; ++m) {
            const vf2 g2 = F0[2][m >> 2], g3 = F0[3][(m >> 1) & 1], g4 = F0[4][m & 1];
            p234[m] = cmul(cmul(c32{ g2.x, g2.y }, c32{ g3.x, g3.y }), c32{ g4.x, g4.y });
        }
        vf2 a[32];
        #pragma unroll
        for (int j = 0; j < 32; ++j) {
            const c32 av = cmul(p01p[j >> 3], p234[j & 7]);
            a[j] = sxor(vf2{ av.x, av.y }, AMASK(j));
        }
        APPLY32R(4, Gr[1][0]); APPLY32R(3, Gr[1][1]); APPLY32R(2, Gr[1][2]);
        APPLY32R(1, Gr[1][3]); APPLY32R(0, Gr[1][4]);
        #pragma unroll
        for (int j = 0; j < 32; ++j)
            *(unsigned*)(stb + (base1 ^ (lswz5(j << 9) << 2))) = pk16(a[j]);
    }
    __syncthreads();

    // ===== Fused 11-pass schedule with deferred-diagonal tables =====
    passB(stb, Gr[1], T[1], base2);                                        __syncthreads();
    passCC(stb, Gr[1], Gr[2], T[2], T[3], base3, C00, C01, C10, C11);      __syncthreads();
    passB(stb, Gr[2], T[4], base2);                                        __syncthreads();
    passAA(stb, Gr[2], Gr[3], T[5], T[6], base1, M00, M01, M10, M11);      __syncthreads();
    passB(stb, Gr[3], T[7], base2);                                        __syncthreads();
    passCC(stb, Gr[3], Gr[4], T[8], T[9], base3, C00, C01, C10, C11);      __syncthreads();
    passB(stb, Gr[4], T[10], base2);                                       __syncthreads();
    passAA(stb, Gr[4], Gr[5], T[11], T[12], base1, M00, M01, M10, M11);    __syncthreads();
    passB(stb, Gr[5], T[13], base2);                                       __syncthreads();
    float se = 0.f, so = 0.f;
    passCLast(stb, Gr[5], T[14], base3, se, so);

    // ---- Reduce + softmax ----
    float local = (__popc(t) & 1) ? (so - se) : (se - so);
    #pragma unroll
    for (int off = 32; off > 0; off >>= 1)
        local += __shfl_down(local, off, 64);
    if ((t & 63) == 0) wsum[t >> 6] = local;
    __syncthreads();
    if (t == 0) {
        float v = 0.0f;
        #pragma unroll
        for (int i = 0; i < NTHREADS / 64; ++i) v += wsum[i];
        const float BETA = 1.0f;
        const float l0 = v * w[0] * BETA, l1 = v * w[1] * BETA;
        const float m  = fmaxf(l0, l1);
        const float e0 = __expf(l0 - m), e1 = __expf(l1 - m);
        const float inv = 1.0f / (e0 + e1);
        out[2 * b + 0] = e0 * inv;
        out[2 * b + 1] = e1 * inv;
    }
}

extern "C" void kernel_launch(void* const* d_in, const int* in_sizes, int n_in,
                              void* d_out, int out_size, void* d_ws, size_t ws_size,
                              hipStream_t stream) {
    const float* x     = (const float*)d_in[0];
    const float* theta = (const float*)d_in[1];
    const float* lam   = (const float*)d_in[2];
    const float* w     = (const float*)d_in[3];
    float* out = (float*)d_out;
    const int batch = in_sizes[0] / NQ;   // 2048
    pqc_kernel<<<batch, NTHREADS, 0, stream>>>(x, theta, lam, w, out);
}